// Round 11
// baseline (2486.170 us; speedup 1.0000x reference)
//
#include <hip/hip_runtime.h>
#include <stdint.h>

#define LDIM 1024
#define DDIM 256
#define FDIM 32
#define NSEG 64
#define BM 32

typedef __attribute__((ext_vector_type(4))) float f32x4;
typedef __attribute__((ext_vector_type(8))) short short8;
typedef __attribute__((ext_vector_type(2))) unsigned int u32x2;
typedef __attribute__((ext_vector_type(4))) unsigned int u32x4;

__device__ __forceinline__ unsigned int pk2bf(float a, float b) {
  union { float f; unsigned int u; } x, y; x.f = a; y.f = b;
  unsigned int ua = x.u + 0x7FFFu + ((x.u >> 16) & 1u);
  unsigned int ub = y.u + 0x7FFFu + ((y.u >> 16) & 1u);
  return (ua >> 16) | (ub & 0xFFFF0000u);
}

__device__ __forceinline__ unsigned short f2bf(float f) {
  union { float f; unsigned int u; } v; v.f = f;
  unsigned int r = v.u + 0x7FFFu + ((v.u >> 16) & 1u);
  return (unsigned short)(r >> 16);
}

__device__ __forceinline__ short8 pack8(f32x4 a, f32x4 b) {
  union { u32x4 u; short8 s; } r;
  r.u[0] = pk2bf(a[0], a[1]); r.u[1] = pk2bf(a[2], a[3]);
  r.u[2] = pk2bf(b[0], b[1]); r.u[3] = pk2bf(b[2], b[3]);
  return r.s;
}

__device__ __forceinline__ float bflo(unsigned int u) {
  union { unsigned int u; float f; } v; v.u = u << 16; return v.f;
}
__device__ __forceinline__ float bfhi(unsigned int u) {
  union { unsigned int u; float f; } v; v.u = u & 0xFFFF0000u; return v.f;
}

// ---- prep: w1tz[f][k] = bf16((W1@Wa1)[k][f]), f=0..31 (z-GEMM B, 64 KB) ----
__global__ void prep_w1tz(const float* __restrict__ W1, const float* __restrict__ Wa1,
                          unsigned short* __restrict__ w1tz) {
  __shared__ float rowf[DDIM];
  const int k = blockIdx.x;
  const int t = threadIdx.x;
  rowf[t] = W1[(size_t)k * DDIM + t];
  __syncthreads();
  if (t < FDIM) {
    float a = 0.f;
    for (int c = 0; c < DDIM; ++c) a += rowf[c] * Wa1[c * FDIM + t];
    w1tz[(size_t)t * LDIM + k] = f2bf(a);
  }
}

// ---- prep: zero Xacc/accE, bz = b1@Wa1 + ba1 ----
__global__ void prep_misc(const float* __restrict__ b1, const float* __restrict__ Wa1,
                          const float* __restrict__ ba1, float* __restrict__ bz,
                          float* __restrict__ Xacc, float* __restrict__ accE) {
  const int b = blockIdx.x, t = threadIdx.x;
  #pragma unroll
  for (int i = 0; i < 4; ++i) Xacc[b * LDIM + i * DDIM + t] = 0.f;
  if (t == 0) accE[b] = 0.f;
  if (b == 0 && t < FDIM) {
    float a = ba1[t];
    for (int c = 0; c < DDIM; ++c) a += b1[c] * Wa1[c * FDIM + t];
    bz[t] = a;
  }
}

// ---- main: single pass over x. z-GEMM (32 cols, B from L2) while parking the
// bf16 x-tile in LDS (64 KB, XOR-swizzled). Epilogue reads the tile back for
// weighted per-segment k-sums. M's big GEMM moved to finalize via linearity.
// r10 NaN root-cause: LDS write offset used f32 scaling and dropped kw*2 ->
// 3/4 of xb uninitialized. Fixed: kb = kw*2 + ktl*128 + kk*64 + g*16. ----
__global__ __launch_bounds__(256, 2) void fused_main(
    const float* __restrict__ x, const int* __restrict__ idxs,
    const unsigned short* __restrict__ w1tz, const float* __restrict__ bz,
    const float* __restrict__ Wa2, const float* __restrict__ ba2,
    float* __restrict__ Xacc, float* __restrict__ accE)
{
  __shared__ __align__(16) unsigned short xb[BM][LDIM];  // 64 KB bf16 x-tile, swizzled
  __shared__ float zlds[BM][33];
  __shared__ float e_lds[BM];
  __shared__ int   seg_lds[BM];

  const int tid = threadIdx.x;
  const int lane = tid & 63;
  const int w = tid >> 6;          // wave owns k-range [w*256, w*256+256)
  const int g = lane >> 4;         // k-subchunk
  const int cl = lane & 15;        // row pair {cl, 16+cl}
  const int row0 = blockIdx.x * BM;
  const int kw = w * 256;

  for (int i = tid; i < BM * 33; i += 256) ((float*)zlds)[i] = 0.f;
  if (tid < BM) seg_lds[tid] = idxs[row0 + tid];
  __syncthreads();

  const float* xa0 = x + (size_t)(row0 + cl) * LDIM + kw + g * 8;   // m=0 row
  const float* xa1 = xa0 + (size_t)16 * LDIM;                        // m=1 row
  const unsigned short* wz = w1tz + kw + (size_t)g * 8;
  // swizzled LDS write bases (row stride 2048 B; swizzle ^((row&7)<<4); rows cl
  // and cl+16 share (row&7) so the same XOR applies to both)
  const int sw = (cl & 7) << 4;
  char* xb0 = (char*)xb + cl * 2048;
  char* xb1 = (char*)xb + (cl + 16) * 2048;

  f32x4 zacc[2][2];
  #pragma unroll
  for (int m = 0; m < 2; ++m)
    #pragma unroll
    for (int n = 0; n < 2; ++n) zacc[m][n] = (f32x4){0.f, 0.f, 0.f, 0.f};

  #pragma unroll
  for (int ktl = 0; ktl < 4; ++ktl) {
    #pragma unroll
    for (int kk = 0; kk < 2; ++kk) {
      // bf16 byte offset within the row for k = kw + ktl*64 + kk*32 + g*8
      const int kb = kw * 2 + ktl * 128 + kk * 64 + g * 16;
      const float* p0 = xa0 + ktl * 64 + kk * 32;
      const float* p1 = xa1 + ktl * 64 + kk * 32;
      short8 a0 = pack8(*(const f32x4*)p0, *(const f32x4*)(p0 + 4));
      short8 a1 = pack8(*(const f32x4*)p1, *(const f32x4*)(p1 + 4));
      *(short8*)(xb0 + (kb ^ sw)) = a0;
      *(short8*)(xb1 + (kb ^ sw)) = a1;
      #pragma unroll
      for (int n = 0; n < 2; ++n) {
        short8 bf = *(const short8*)(wz + (size_t)(n * 16 + cl) * LDIM + ktl * 64 + kk * 32);
        zacc[0][n] = __builtin_amdgcn_mfma_f32_16x16x32_bf16(a0, bf, zacc[0][n], 0, 0, 0);
        zacc[1][n] = __builtin_amdgcn_mfma_f32_16x16x32_bf16(a1, bf, zacc[1][n], 0, 0, 0);
      }
    }
  }

  // K-split z partials -> LDS atomics (row = m*16+g*4+q, col = n*16+cl)
  #pragma unroll
  for (int m = 0; m < 2; ++m)
    #pragma unroll
    for (int n = 0; n < 2; ++n)
      #pragma unroll
      for (int q = 0; q < 4; ++q)
        atomicAdd(&zlds[m * 16 + g * 4 + q][n * 16 + cl], zacc[m][n][q]);
  __syncthreads();   // zlds + xb complete

  if (tid < BM) {
    float lg = 0.f;
    #pragma unroll
    for (int c = 0; c < 32; ++c) {
      float e2 = exp2f((zlds[tid][c] + bz[c]) * 2.8853900817779268f);  // e^{2z}
      lg += (1.f - 2.f / (e2 + 1.f)) * Wa2[c];                         // tanh(z)*Wa2
    }
    float e = expf(lg + ba2[0]);    // |logit| bounded by tanh -> no max pass
    e_lds[tid] = e;
    atomicAdd(&accE[seg_lds[tid]], e);
  }
  __syncthreads();

  // ---- weighted per-k column sums from the LDS tile ----
  // thread t owns 4 k-values: bytes [t*8, t*8+8) of each row = k in [t*4, t*4+4)
  const int smin = seg_lds[0];
  const int smax = seg_lds[BM - 1];
  const int tb = tid * 8;
  for (int s = smin; s <= smax; ++s) {
    float s0 = 0.f, s1 = 0.f, s2 = 0.f, s3 = 0.f;
    #pragma unroll
    for (int r = 0; r < BM; ++r) {
      const float wr = (seg_lds[r] == s) ? e_lds[r] : 0.f;
      u32x2 v = *(const u32x2*)((const char*)xb + r * 2048 + (tb ^ ((r & 7) << 4)));
      s0 += wr * bflo(v[0]); s1 += wr * bfhi(v[0]);
      s2 += wr * bflo(v[1]); s3 += wr * bfhi(v[1]);
    }
    float* dst = Xacc + s * LDIM + tid * 4;
    atomicAdd(dst + 0, s0); atomicAdd(dst + 1, s1);
    atomicAdd(dst + 2, s2); atomicAdd(dst + 3, s3);
  }
}

// ---- finalize: M[s] = (Xacc[s]/E)@W1 + b1 (f32 W1); proj = normalize(M@Wp+bp) ----
__global__ void finalize_k(const float* __restrict__ Xacc, const float* __restrict__ accE,
                           const float* __restrict__ W1, const float* __restrict__ b1,
                           const float* __restrict__ Wp, const float* __restrict__ bp,
                           float* __restrict__ out) {
  __shared__ float Xn[LDIM];
  __shared__ float Ml[DDIM];
  const int s = blockIdx.x, t = threadIdx.x;
  const float E = accE[s];
  const float inv = (E > 0.f) ? 1.f / E : 0.f;
  #pragma unroll
  for (int i = 0; i < 4; ++i) Xn[i * DDIM + t] = Xacc[s * LDIM + i * DDIM + t] * inv;
  __syncthreads();
  float m = 0.f;
  for (int k = 0; k < LDIM; ++k) m += Xn[k] * W1[(size_t)k * DDIM + t];
  m = (E > 0.f) ? (m + b1[t]) : 0.f;   // empty segment -> M = 0 (matches reference)
  out[s * DDIM + t] = m;
  Ml[t] = m;
  __syncthreads();
  if (t < FDIM) {
    float p = bp[t];
    for (int c = 0; c < DDIM; ++c) p += Ml[c] * Wp[c * FDIM + t];
    float n2 = p * p;
    #pragma unroll
    for (int mask = 1; mask <= 16; mask <<= 1) n2 += __shfl_xor(n2, mask);
    out[NSEG * DDIM + s * FDIM + t] = p / fmaxf(sqrtf(n2), 1e-12f);
  }
}

extern "C" void kernel_launch(void* const* d_in, const int* in_sizes, int n_in,
                              void* d_out, int out_size, void* d_ws, size_t ws_size,
                              hipStream_t stream) {
  const float* x   = (const float*)d_in[0];
  const int*   idxs= (const int*)d_in[1];
  const float* W1  = (const float*)d_in[2];
  const float* b1  = (const float*)d_in[3];
  const float* Wa1 = (const float*)d_in[4];
  const float* ba1 = (const float*)d_in[5];
  const float* Wa2 = (const float*)d_in[6];
  const float* ba2 = (const float*)d_in[7];
  const float* Wp  = (const float*)d_in[8];
  const float* bp  = (const float*)d_in[9];
  float* out = (float*)d_out;

  char* ws = (char*)d_ws;
  unsigned short* w1tz = (unsigned short*)ws;         // 32*1024 bf16 = 65536 B
  float* bz   = (float*)(ws + 65536);                 // 32 f32
  float* Xacc = (float*)(ws + 65536 + 256);           // 64*1024 f32 = 262144 B
  float* accE = (float*)(ws + 65536 + 256 + 262144);  // 64 f32

  const int n = in_sizes[1];                          // 262144 rows
  prep_w1tz<<<LDIM, DDIM, 0, stream>>>(W1, Wa1, w1tz);
  prep_misc<<<NSEG, DDIM, 0, stream>>>(b1, Wa1, ba1, bz, Xacc, accE);
  fused_main<<<n / BM, 256, 0, stream>>>(x, idxs, w1tz, bz, Wa2, ba2, Xacc, accE);
  finalize_k<<<NSEG, DDIM, 0, stream>>>(Xacc, accE, W1, b1, Wp, bp, out);
}